// Round 1
// baseline (73.017 us; speedup 1.0000x reference)
//
#include <hip/hip_runtime.h>

// Logm of 2*2^20 independent 3x3 SPD matrices.
// Layout: x[b][c][v], c = 3*i+j, plane stride NV = 2^20 floats.
// Algorithm: 6 cyclic Jacobi sweeps (branchless) -> U, lambda; Y = U log(L) U^T.

#define NV (1 << 20)   // D*H*W = 64*128*128
#define BT 2

__device__ __forceinline__ void jacobi_rot(
    float &app, float &aqq, float &apq, float &arp, float &arq,
    float &v0p, float &v0q, float &v1p, float &v1q, float &v2p, float &v2q)
{
    // NR-style rotation: t = sign(theta)/(|theta|+sqrt(theta^2+1))
    float theta = (aqq - app) * 0.5f / apq;                 // may be inf/nan if apq==0
    float t = copysignf(1.0f, theta) /
              (fabsf(theta) + sqrtf(fmaf(theta, theta, 1.0f)));
    if (fabsf(apq) < 1e-20f) t = 0.0f;                      // guard 0/0 -> NaN case
    float c = rsqrtf(fmaf(t, t, 1.0f));
    float s = t * c;

    app = fmaf(-t, apq, app);
    aqq = fmaf( t, apq, aqq);
    apq = 0.0f;

    float rp = arp, rq = arq;
    arp = fmaf(c, rp, -s * rq);
    arq = fmaf(s, rp,  c * rq);

    float x0;
    x0 = v0p; v0p = fmaf(c, x0, -s * v0q); v0q = fmaf(s, x0, c * v0q);
    x0 = v1p; v1p = fmaf(c, x0, -s * v1q); v1q = fmaf(s, x0, c * v1q);
    x0 = v2p; v2p = fmaf(c, x0, -s * v2q); v2q = fmaf(s, x0, c * v2q);
}

extern "C" __global__ void __launch_bounds__(256)
logm_kernel(const float* __restrict__ x, float* __restrict__ y)
{
    long long t  = (long long)blockIdx.x * blockDim.x + threadIdx.x;
    long long g  = t * 4;                      // first voxel id handled by this thread
    if (g >= (long long)BT * NV) return;
    int b = (int)(g >> 20);
    int v = (int)(g & (NV - 1));
    const float* xb = x + ((long long)b * 9) * NV + v;
    float*       yb = y + ((long long)b * 9) * NV + v;

    float in[9][4];
#pragma unroll
    for (int c = 0; c < 9; ++c)
        *reinterpret_cast<float4*>(&in[c][0]) =
            *reinterpret_cast<const float4*>(xb + (long long)c * NV);

    float outv[9][4];

#pragma unroll
    for (int j = 0; j < 4; ++j) {
        float m00 = in[0][j], m11 = in[4][j], m22 = in[8][j];
        float m01 = 0.5f * (in[1][j] + in[3][j]);
        float m02 = 0.5f * (in[2][j] + in[6][j]);
        float m12 = 0.5f * (in[5][j] + in[7][j]);

        float v00 = 1.f, v01 = 0.f, v02 = 0.f;
        float v10 = 0.f, v11 = 1.f, v12 = 0.f;
        float v20 = 0.f, v21 = 0.f, v22 = 1.f;

#pragma unroll
        for (int sw = 0; sw < 6; ++sw) {
            // (p,q)=(0,1), r=2: off-diag pair (m02,m12), V cols 0,1
            jacobi_rot(m00, m11, m01, m02, m12,
                       v00, v01, v10, v11, v20, v21);
            // (p,q)=(0,2), r=1: off-diag pair (m01,m12), V cols 0,2
            jacobi_rot(m00, m22, m02, m01, m12,
                       v00, v02, v10, v12, v20, v22);
            // (p,q)=(1,2), r=0: off-diag pair (m01,m02), V cols 1,2
            jacobi_rot(m11, m22, m12, m01, m02,
                       v01, v02, v11, v12, v21, v22);
        }

        float l0 = __logf(fmaxf(m00, 1e-30f));
        float l1 = __logf(fmaxf(m11, 1e-30f));
        float l2 = __logf(fmaxf(m22, 1e-30f));

        float y00 = l0*v00*v00 + l1*v01*v01 + l2*v02*v02;
        float y11 = l0*v10*v10 + l1*v11*v11 + l2*v12*v12;
        float y22 = l0*v20*v20 + l1*v21*v21 + l2*v22*v22;
        float y01 = l0*v00*v10 + l1*v01*v11 + l2*v02*v12;
        float y02 = l0*v00*v20 + l1*v01*v21 + l2*v02*v22;
        float y12 = l0*v10*v20 + l1*v11*v21 + l2*v12*v22;

        outv[0][j] = y00; outv[1][j] = y01; outv[2][j] = y02;
        outv[3][j] = y01; outv[4][j] = y11; outv[5][j] = y12;
        outv[6][j] = y02; outv[7][j] = y12; outv[8][j] = y22;
    }

#pragma unroll
    for (int c = 0; c < 9; ++c)
        *reinterpret_cast<float4*>(yb + (long long)c * NV) =
            *reinterpret_cast<float4*>(&outv[c][0]);
}

extern "C" void kernel_launch(void* const* d_in, const int* in_sizes, int n_in,
                              void* d_out, int out_size, void* d_ws, size_t ws_size,
                              hipStream_t stream) {
    const float* x = (const float*)d_in[0];
    float*       y = (float*)d_out;
    const int total_threads = BT * NV / 4;          // 524288
    dim3 grid(total_threads / 256), block(256);
    hipLaunchKernelGGL(logm_kernel, grid, block, 0, stream, x, y);
}

// Round 4
// 38.272 us; speedup vs baseline: 1.9079x; 1.9079x over previous
//
#include <hip/hip_runtime.h>

// Logm of 2*2^20 independent 3x3 SPD matrices.
// Layout: x[b][c][v], c = 3*i+j, plane stride NV = 2^20 floats.
// Cyclic Jacobi, 5 sweeps, half-angle rotation (2x v_rsq, no div/sqrt chains).
// NR-equivalent: theta=(aqq-app)/(2h), t=sgn(theta)/(|theta|+sqrt(theta^2+1)).
// Half-angle: u=(app-aqq)/2, r=sqrt(u^2+h^2), cos2p=|u|/r, c=sqrt((1+cos2p)/2),
//   s = -h*sign(u)/(2*r*c)   [h keeps its OWN sign -- copysignf(h,u) was the bug],
//   t = s/c, app' = app - t*h, aqq' = aqq + t*h.
// Verified in all 4 sign quadrants of (u,h) against the NR closed form.

#define NV (1 << 20)   // D*H*W
#define BT 2

__device__ __forceinline__ void jacobi_rot(
    float &app, float &aqq, float &apq, float &arp, float &arq,
    float &v0p, float &v0q, float &v1p, float &v1q, float &v2p, float &v2q)
{
    float h  = apq;
    float u  = 0.5f * (app - aqq);
    float r2 = fmaf(u, u, h * h);
    float rinv = __builtin_amdgcn_rsqf(r2);            // 1/r
    float co   = fabsf(u) * rinv;                      // cos(2theta) >= 0
    float c2   = fmaf(0.5f, co, 0.5f);                 // cos^2(theta)
    float cinv = __builtin_amdgcn_rsqf(c2);            // 1/c
    float c    = c2 * cinv;
    float s    = -0.5f * h * copysignf(1.0f, u) * rinv * cinv;  // -sign(u)*h/(2rc)
    float t    = s * cinv;                             // tan(theta)
    if (r2 < 1e-30f) { c = 1.0f; s = 0.0f; t = 0.0f; } // u==h==0 guard

    app = fmaf(-t, h, app);
    aqq = fmaf( t, h, aqq);
    apq = 0.0f;

    float rp = arp, rq = arq;
    arp = fmaf(c, rp, -s * rq);
    arq = fmaf(s, rp,  c * rq);

    float x0;
    x0 = v0p; v0p = fmaf(c, x0, -s * v0q); v0q = fmaf(s, x0, c * v0q);
    x0 = v1p; v1p = fmaf(c, x0, -s * v1q); v1q = fmaf(s, x0, c * v1q);
    x0 = v2p; v2p = fmaf(c, x0, -s * v2q); v2q = fmaf(s, x0, c * v2q);
}

extern "C" __global__ void __launch_bounds__(256)
logm_kernel(const float* __restrict__ x, float* __restrict__ y)
{
    long long t  = (long long)blockIdx.x * blockDim.x + threadIdx.x;
    long long g  = t * 4;
    if (g >= (long long)BT * NV) return;
    int b = (int)(g >> 20);
    int v = (int)(g & (NV - 1));
    const float* xb = x + ((long long)b * 9) * NV + v;
    float*       yb = y + ((long long)b * 9) * NV + v;

    float in[9][4];
#pragma unroll
    for (int c = 0; c < 9; ++c)
        *reinterpret_cast<float4*>(&in[c][0]) =
            *reinterpret_cast<const float4*>(xb + (long long)c * NV);

    float outv[9][4];

#pragma unroll
    for (int j = 0; j < 4; ++j) {
        float m00 = in[0][j], m11 = in[4][j], m22 = in[8][j];
        float m01 = 0.5f * (in[1][j] + in[3][j]);
        float m02 = 0.5f * (in[2][j] + in[6][j]);
        float m12 = 0.5f * (in[5][j] + in[7][j]);

        float v00 = 1.f, v01 = 0.f, v02 = 0.f;
        float v10 = 0.f, v11 = 1.f, v12 = 0.f;
        float v20 = 0.f, v21 = 0.f, v22 = 1.f;

#pragma unroll
        for (int sw = 0; sw < 5; ++sw) {
            jacobi_rot(m00, m11, m01, m02, m12,
                       v00, v01, v10, v11, v20, v21);
            jacobi_rot(m00, m22, m02, m01, m12,
                       v00, v02, v10, v12, v20, v22);
            jacobi_rot(m11, m22, m12, m01, m02,
                       v01, v02, v11, v12, v21, v22);
        }

        float l0 = __logf(fmaxf(m00, 1e-30f));
        float l1 = __logf(fmaxf(m11, 1e-30f));
        float l2 = __logf(fmaxf(m22, 1e-30f));

        float y00 = l0*v00*v00 + l1*v01*v01 + l2*v02*v02;
        float y11 = l0*v10*v10 + l1*v11*v11 + l2*v12*v12;
        float y22 = l0*v20*v20 + l1*v21*v21 + l2*v22*v22;
        float y01 = l0*v00*v10 + l1*v01*v11 + l2*v02*v12;
        float y02 = l0*v00*v20 + l1*v01*v21 + l2*v02*v22;
        float y12 = l0*v10*v20 + l1*v11*v21 + l2*v12*v22;

        outv[0][j] = y00; outv[1][j] = y01; outv[2][j] = y02;
        outv[3][j] = y01; outv[4][j] = y11; outv[5][j] = y12;
        outv[6][j] = y02; outv[7][j] = y12; outv[8][j] = y22;
    }

#pragma unroll
    for (int c = 0; c < 9; ++c)
        *reinterpret_cast<float4*>(yb + (long long)c * NV) =
            *reinterpret_cast<float4*>(&outv[c][0]);
}

extern "C" void kernel_launch(void* const* d_in, const int* in_sizes, int n_in,
                              void* d_out, int out_size, void* d_ws, size_t ws_size,
                              hipStream_t stream) {
    const float* x = (const float*)d_in[0];
    float*       y = (float*)d_out;
    const int total_threads = BT * NV / 4;
    dim3 grid(total_threads / 256), block(256);
    hipLaunchKernelGGL(logm_kernel, grid, block, 0, stream, x, y);
}

// Round 5
// 35.628 us; speedup vs baseline: 2.0494x; 1.0742x over previous
//
#include <hip/hip_runtime.h>

// Logm of 2*2^20 independent 3x3 SPD matrices.
// Layout: x[b][c][v], c = 3*i+j, plane stride NV = 2^20 floats.
// Cyclic Jacobi, 4 sweeps, half-angle rotation (2x v_rsq, no div/sqrt chains).
// SoA restructure: voxel loop INSIDE each rotation step -> 4 independent
// dependency chains adjacent for the scheduler (ILP=4 on trans+FMA pipes).
// Rotation (verified all 4 sign quadrants vs NR closed form, passed round 4):
//   u=(app-aqq)/2, h=apq, r=sqrt(u^2+h^2), c=sqrt((1+|u|/r)/2),
//   s=-h*sign(u)/(2rc), t=s/c, app'=app-t*h, aqq'=aqq+t*h.

#define NV (1 << 20)   // D*H*W
#define BT 2

__device__ __forceinline__ void jacobi_rot(
    float &app, float &aqq, float &apq, float &arp, float &arq,
    float &v0p, float &v0q, float &v1p, float &v1q, float &v2p, float &v2q)
{
    float h  = apq;
    float u  = 0.5f * (app - aqq);
    float r2 = fmaf(u, u, h * h);
    float rinv = __builtin_amdgcn_rsqf(r2);            // 1/r
    float co   = fabsf(u) * rinv;                      // cos(2theta) >= 0
    float c2   = fmaf(0.5f, co, 0.5f);                 // cos^2(theta)
    float cinv = __builtin_amdgcn_rsqf(c2);            // 1/c
    float c    = c2 * cinv;
    float s    = -0.5f * h * copysignf(1.0f, u) * rinv * cinv;  // -sign(u)*h/(2rc)
    float t    = s * cinv;                             // tan(theta)
    if (r2 < 1e-30f) { c = 1.0f; s = 0.0f; t = 0.0f; } // u==h==0 guard

    app = fmaf(-t, h, app);
    aqq = fmaf( t, h, aqq);
    apq = 0.0f;

    float rp = arp, rq = arq;
    arp = fmaf(c, rp, -s * rq);
    arq = fmaf(s, rp,  c * rq);

    float x0;
    x0 = v0p; v0p = fmaf(c, x0, -s * v0q); v0q = fmaf(s, x0, c * v0q);
    x0 = v1p; v1p = fmaf(c, x0, -s * v1q); v1q = fmaf(s, x0, c * v1q);
    x0 = v2p; v2p = fmaf(c, x0, -s * v2q); v2q = fmaf(s, x0, c * v2q);
}

extern "C" __global__ void __launch_bounds__(256)
logm_kernel(const float* __restrict__ x, float* __restrict__ y)
{
    long long t  = (long long)blockIdx.x * blockDim.x + threadIdx.x;
    long long g  = t * 4;
    if (g >= (long long)BT * NV) return;
    int b = (int)(g >> 20);
    int v = (int)(g & (NV - 1));
    const float* xb = x + ((long long)b * 9) * NV + v;
    float*       yb = y + ((long long)b * 9) * NV + v;

    float in[9][4];
#pragma unroll
    for (int c = 0; c < 9; ++c)
        *reinterpret_cast<float4*>(&in[c][0]) =
            *reinterpret_cast<const float4*>(xb + (long long)c * NV);

    // SoA state: all indices compile-time constant -> registers
    float M00[4], M11[4], M22[4], M01[4], M02[4], M12[4];
    float V00[4], V01[4], V02[4], V10[4], V11[4], V12[4], V20[4], V21[4], V22[4];

#pragma unroll
    for (int j = 0; j < 4; ++j) {
        M00[j] = in[0][j]; M11[j] = in[4][j]; M22[j] = in[8][j];
        M01[j] = 0.5f * (in[1][j] + in[3][j]);
        M02[j] = 0.5f * (in[2][j] + in[6][j]);
        M12[j] = 0.5f * (in[5][j] + in[7][j]);
        V00[j] = 1.f; V01[j] = 0.f; V02[j] = 0.f;
        V10[j] = 0.f; V11[j] = 1.f; V12[j] = 0.f;
        V20[j] = 0.f; V21[j] = 0.f; V22[j] = 1.f;
    }

#pragma unroll
    for (int sw = 0; sw < 4; ++sw) {
        // (p,q)=(0,1): 4 independent chains adjacent
#pragma unroll
        for (int j = 0; j < 4; ++j)
            jacobi_rot(M00[j], M11[j], M01[j], M02[j], M12[j],
                       V00[j], V01[j], V10[j], V11[j], V20[j], V21[j]);
        // (p,q)=(0,2)
#pragma unroll
        for (int j = 0; j < 4; ++j)
            jacobi_rot(M00[j], M22[j], M02[j], M01[j], M12[j],
                       V00[j], V02[j], V10[j], V12[j], V20[j], V22[j]);
        // (p,q)=(1,2)
#pragma unroll
        for (int j = 0; j < 4; ++j)
            jacobi_rot(M11[j], M22[j], M12[j], M01[j], M02[j],
                       V01[j], V02[j], V11[j], V12[j], V21[j], V22[j]);
    }

    float L0[4], L1[4], L2[4];
#pragma unroll
    for (int j = 0; j < 4; ++j) {
        L0[j] = __logf(fmaxf(M00[j], 1e-30f));
        L1[j] = __logf(fmaxf(M11[j], 1e-30f));
        L2[j] = __logf(fmaxf(M22[j], 1e-30f));
    }

    float outv[9][4];
#pragma unroll
    for (int j = 0; j < 4; ++j) {
        float y00 = L0[j]*V00[j]*V00[j] + L1[j]*V01[j]*V01[j] + L2[j]*V02[j]*V02[j];
        float y11 = L0[j]*V10[j]*V10[j] + L1[j]*V11[j]*V11[j] + L2[j]*V12[j]*V12[j];
        float y22 = L0[j]*V20[j]*V20[j] + L1[j]*V21[j]*V21[j] + L2[j]*V22[j]*V22[j];
        float y01 = L0[j]*V00[j]*V10[j] + L1[j]*V01[j]*V11[j] + L2[j]*V02[j]*V12[j];
        float y02 = L0[j]*V00[j]*V20[j] + L1[j]*V01[j]*V21[j] + L2[j]*V02[j]*V22[j];
        float y12 = L0[j]*V10[j]*V20[j] + L1[j]*V11[j]*V21[j] + L2[j]*V12[j]*V22[j];
        outv[0][j] = y00; outv[1][j] = y01; outv[2][j] = y02;
        outv[3][j] = y01; outv[4][j] = y11; outv[5][j] = y12;
        outv[6][j] = y02; outv[7][j] = y12; outv[8][j] = y22;
    }

#pragma unroll
    for (int c = 0; c < 9; ++c)
        *reinterpret_cast<float4*>(yb + (long long)c * NV) =
            *reinterpret_cast<float4*>(&outv[c][0]);
}

extern "C" void kernel_launch(void* const* d_in, const int* in_sizes, int n_in,
                              void* d_out, int out_size, void* d_ws, size_t ws_size,
                              hipStream_t stream) {
    const float* x = (const float*)d_in[0];
    float*       y = (float*)d_out;
    const int total_threads = BT * NV / 4;
    dim3 grid(total_threads / 256), block(256);
    hipLaunchKernelGGL(logm_kernel, grid, block, 0, stream, x, y);
}